// Round 2
// baseline (3813.651 us; speedup 1.0000x reference)
//
#include <hip/hip_runtime.h>
#include <float.h>

#define N_NODES 20000
#define N_EDGES 320000
#define DIM     128
#define CB      12000
#define NG      256
#define NL      5

// ---------------------------------------------------------------- CSR build
__global__ void k_deg(const int* __restrict__ dst, int* __restrict__ deg) {
  int e = blockIdx.x * 256 + threadIdx.x;
  if (e < N_EDGES) atomicAdd(&deg[dst[e]], 1);
}

__global__ void k_scan(const int* __restrict__ deg, int* __restrict__ rowptr) {
  __shared__ int buf[256];
  int t = threadIdx.x;
  int carry = 0;
  for (int base = 0; base < N_NODES; base += 256) {
    int v = (base + t < N_NODES) ? deg[base + t] : 0;
    buf[t] = v;
    __syncthreads();
    for (int off = 1; off < 256; off <<= 1) {
      int a = (t >= off) ? buf[t - off] : 0;
      __syncthreads();
      buf[t] += a;
      __syncthreads();
    }
    if (base + t < N_NODES) rowptr[base + t] = carry + buf[t] - v;
    carry += buf[255];
    __syncthreads();
  }
  if (t == 0) rowptr[N_NODES] = carry;
}

__global__ void k_fill(const int* __restrict__ src, const int* __restrict__ dst,
                       const int* __restrict__ rowptr, int* __restrict__ cursor,
                       int* __restrict__ eidx) {
  int e = blockIdx.x * 256 + threadIdx.x;
  if (e < N_EDGES) {
    int d = dst[e];
    int p = atomicAdd(&cursor[d], 1);
    eidx[rowptr[d] + p] = src[e];
  }
}

// ------------------------------------------------- row squared-norm, numpy-pairwise-exact
// Replicates numpy's pairwise summation for n=128 (8 accumulators striding 8,
// sequential 16 terms each, then ((r0+r1)+(r2+r3))+((r4+r5)+(r6+r7)) ).
__global__ void k_rowsq_np(const float* __restrict__ in, float* __restrict__ out, int n) {
  int t = blockIdx.x * 256 + threadIdx.x;
  int row = t >> 3, j = t & 7;
  if (row >= n) return;
  const float* p = &in[row * DIM];
  float v0 = p[j];
  float r = v0 * v0;
#pragma unroll
  for (int i = 1; i < 16; ++i) {
    float v = p[i * 8 + j];
    r += v * v;
  }
  // IEEE add commutes, so xor-butterfly reproduces numpy's combine tree exactly
  r += __shfl_xor(r, 1);
  r += __shfl_xor(r, 2);
  r += __shfl_xor(r, 4);
  if (j == 0) out[row] = r;
}

// wave-per-node gather: z0[i] = h[i] + sum_{j->i} h[j]
__global__ void k_gather(const float* __restrict__ hin, const int* __restrict__ rowptr,
                         const int* __restrict__ eidx, float* __restrict__ z0) {
  int w = (blockIdx.x * blockDim.x + threadIdx.x) >> 6;
  int lane = threadIdx.x & 63;
  if (w >= N_NODES) return;
  const float2* hp = (const float2*)hin;
  int beg = rowptr[w], end = rowptr[w + 1];
  float2 acc = hp[w * 64 + lane];
  for (int e = beg; e < end; ++e) {
    int s = eidx[e];
    float2 v = hp[s * 64 + lane];
    acc.x += v.x; acc.y += v.y;
  }
  ((float2*)z0)[w * 64 + lane] = acc;
}

// fused MLP: z2 = relu(relu(z0@W1+b1)@W2+b2), write z2, accumulate BN stats
__launch_bounds__(256, 1)
__global__ void k_mlp(const float* __restrict__ z0,
                      const float* __restrict__ W1, const float* __restrict__ b1,
                      const float* __restrict__ W2, const float* __restrict__ b2,
                      float* __restrict__ hout, float* __restrict__ stats) {
  __shared__ float sA[64][132];
  __shared__ float sW[128][132];
  __shared__ float sStat[256];
  const int t = threadIdx.x;
  const int R0 = blockIdx.x * 64;
  sStat[t] = 0.0f;
#pragma unroll
  for (int q = 0; q < 8; ++q) {          // stage z0 tile 64x128
    int flat = q * 256 + t;
    int r = flat >> 5, c4 = (flat & 31) << 2;
    float4 v = make_float4(0.f, 0.f, 0.f, 0.f);
    if (R0 + r < N_NODES) v = *(const float4*)&z0[(R0 + r) * DIM + c4];
    *(float4*)&sA[r][c4] = v;
  }
#pragma unroll
  for (int q = 0; q < 16; ++q) {         // stage W1 128x128
    int flat = q * 256 + t;
    int r = flat >> 5, c4 = (flat & 31) << 2;
    *(float4*)&sW[r][c4] = *(const float4*)&W1[r * DIM + c4];
  }
  __syncthreads();
  const int rg = t >> 4, cg = t & 15;    // rows rg*4+i, cols cg*8+j
  float z1v[4][8];
  {
    float acc[4][8];
#pragma unroll
    for (int j = 0; j < 8; ++j) {
      float bj = b1[cg * 8 + j];
#pragma unroll
      for (int i = 0; i < 4; ++i) acc[i][j] = bj;
    }
    for (int k = 0; k < DIM; k += 4) {
      __align__(16) float Ar[4][4];
#pragma unroll
      for (int i = 0; i < 4; ++i) *(float4*)Ar[i] = *(const float4*)&sA[rg * 4 + i][k];
#pragma unroll
      for (int kk = 0; kk < 4; ++kk) {
        float4 wlo = *(const float4*)&sW[k + kk][cg * 8];
        float4 whi = *(const float4*)&sW[k + kk][cg * 8 + 4];
        float w[8] = {wlo.x, wlo.y, wlo.z, wlo.w, whi.x, whi.y, whi.z, whi.w};
#pragma unroll
        for (int i = 0; i < 4; ++i)
#pragma unroll
          for (int j = 0; j < 8; ++j) acc[i][j] += Ar[i][kk] * w[j];
      }
    }
#pragma unroll
    for (int i = 0; i < 4; ++i)
#pragma unroll
      for (int j = 0; j < 8; ++j) z1v[i][j] = fmaxf(acc[i][j], 0.f);
  }
  __syncthreads();
#pragma unroll
  for (int i = 0; i < 4; ++i) {          // z1 -> sA
    *(float4*)&sA[rg * 4 + i][cg * 8]     = make_float4(z1v[i][0], z1v[i][1], z1v[i][2], z1v[i][3]);
    *(float4*)&sA[rg * 4 + i][cg * 8 + 4] = make_float4(z1v[i][4], z1v[i][5], z1v[i][6], z1v[i][7]);
  }
#pragma unroll
  for (int q = 0; q < 16; ++q) {         // stage W2
    int flat = q * 256 + t;
    int r = flat >> 5, c4 = (flat & 31) << 2;
    *(float4*)&sW[r][c4] = *(const float4*)&W2[r * DIM + c4];
  }
  __syncthreads();
  float z2v[4][8];
  {
    float acc[4][8];
#pragma unroll
    for (int j = 0; j < 8; ++j) {
      float bj = b2[cg * 8 + j];
#pragma unroll
      for (int i = 0; i < 4; ++i) acc[i][j] = bj;
    }
    for (int k = 0; k < DIM; k += 4) {
      __align__(16) float Ar[4][4];
#pragma unroll
      for (int i = 0; i < 4; ++i) *(float4*)Ar[i] = *(const float4*)&sA[rg * 4 + i][k];
#pragma unroll
      for (int kk = 0; kk < 4; ++kk) {
        float4 wlo = *(const float4*)&sW[k + kk][cg * 8];
        float4 whi = *(const float4*)&sW[k + kk][cg * 8 + 4];
        float w[8] = {wlo.x, wlo.y, wlo.z, wlo.w, whi.x, whi.y, whi.z, whi.w};
#pragma unroll
        for (int i = 0; i < 4; ++i)
#pragma unroll
          for (int j = 0; j < 8; ++j) acc[i][j] += Ar[i][kk] * w[j];
      }
    }
#pragma unroll
    for (int i = 0; i < 4; ++i)
#pragma unroll
      for (int j = 0; j < 8; ++j) z2v[i][j] = fmaxf(acc[i][j], 0.f);
  }
  // store + stats
#pragma unroll
  for (int i = 0; i < 4; ++i) {
    int r = R0 + rg * 4 + i;
    if (r < N_NODES) {
      *(float4*)&hout[r * DIM + cg * 8]     = make_float4(z2v[i][0], z2v[i][1], z2v[i][2], z2v[i][3]);
      *(float4*)&hout[r * DIM + cg * 8 + 4] = make_float4(z2v[i][4], z2v[i][5], z2v[i][6], z2v[i][7]);
    }
  }
#pragma unroll
  for (int j = 0; j < 8; ++j) {
    float s = 0.f, ss = 0.f;
#pragma unroll
    for (int i = 0; i < 4; ++i) {
      if (R0 + rg * 4 + i < N_NODES) { float v = z2v[i][j]; s += v; ss += v * v; }
    }
    atomicAdd(&sStat[cg * 8 + j], s);
    atomicAdd(&sStat[128 + cg * 8 + j], ss);
  }
  __syncthreads();
  atomicAdd(&stats[t], sStat[t]);
}

__global__ void k_bn(float* __restrict__ h, const float* __restrict__ stats,
                     const float* __restrict__ gamma, const float* __restrict__ beta) {
  int idx = blockIdx.x * 256 + threadIdx.x;
  if (idx >= N_NODES * DIM / 4) return;
  int c4 = (idx & 31) << 2;
  float4 v = *(float4*)&h[idx * 4];
  const float* vv = (const float*)&v;
  float r[4];
#pragma unroll
  for (int m = 0; m < 4; ++m) {
    int c = c4 + m;
    float mu  = stats[c] / (float)N_NODES;
    float var = stats[128 + c] / (float)N_NODES - mu * mu;
    float is  = rsqrtf(var + 1e-5f);
    r[m] = (vv[m] - mu) * is * gamma[c] + beta[c];
  }
  *(float4*)&h[idx * 4] = make_float4(r[0], r[1], r[2], r[3]);
}

// ---------------------------------------------------------------- VQ argmin
// f64-exact dot, rounded to f32, then d2 = (x2 - 2*dot) + c2 in f32 in numpy's
// exact expression order. Tie-break: lowest index (np.argmin semantics).
__launch_bounds__(256, 2)
__global__ void k_vq(const float* __restrict__ h, const float* __restrict__ x2,
                     const float* __restrict__ cbk, const float* __restrict__ c2,
                     int* __restrict__ vqidx) {
  __shared__ float sX[64][132];
  __shared__ float sC[64][132];
  __shared__ float sc2[64];
  const int t = threadIdx.x;
  const int R0 = blockIdx.x * 64;
#pragma unroll
  for (int q = 0; q < 8; ++q) {
    int flat = q * 256 + t;
    int r = flat >> 5, c4 = (flat & 31) << 2;
    float4 v = make_float4(0.f, 0.f, 0.f, 0.f);
    if (R0 + r < N_NODES) v = *(const float4*)&h[(R0 + r) * DIM + c4];
    *(float4*)&sX[r][c4] = v;
  }
  const int rg = t >> 4, cg = t & 15;    // rows rg*4+i, cols cg*4+j
  float xs[4];
#pragma unroll
  for (int i = 0; i < 4; ++i) {
    int r = R0 + rg * 4 + i;
    xs[i] = (r < N_NODES) ? x2[r] : 0.f;
  }
  float best[4] = {FLT_MAX, FLT_MAX, FLT_MAX, FLT_MAX};
  int bidx[4] = {0, 0, 0, 0};
  for (int C0 = 0; C0 < 12032; C0 += 64) {
    __syncthreads();
#pragma unroll
    for (int q = 0; q < 8; ++q) {
      int flat = q * 256 + t;
      int r = flat >> 5, c4 = (flat & 31) << 2;
      float4 v = make_float4(0.f, 0.f, 0.f, 0.f);
      if (C0 + r < CB) v = *(const float4*)&cbk[(C0 + r) * DIM + c4];
      *(float4*)&sC[r][c4] = v;
    }
    if (t < 64) sc2[t] = (C0 + t < CB) ? c2[C0 + t] : 1e30f;
    __syncthreads();
    double acc[4][4] = {};
    for (int k = 0; k < DIM; k += 4) {
      __align__(16) float Ar[4][4], Br[4][4];
#pragma unroll
      for (int i = 0; i < 4; ++i) *(float4*)Ar[i] = *(const float4*)&sX[rg * 4 + i][k];
#pragma unroll
      for (int j = 0; j < 4; ++j) *(float4*)Br[j] = *(const float4*)&sC[cg * 4 + j][k];
#pragma unroll
      for (int kk = 0; kk < 4; ++kk)
#pragma unroll
        for (int i = 0; i < 4; ++i)
#pragma unroll
          for (int j = 0; j < 4; ++j)
            acc[i][j] = fma((double)Ar[i][kk], (double)Br[j][kk], acc[i][j]);
    }
#pragma unroll
    for (int i = 0; i < 4; ++i)
#pragma unroll
      for (int j = 0; j < 4; ++j) {
        float dot = (float)acc[i][j];                 // correctly-rounded dot
        float d = (xs[i] - 2.0f * dot) + sc2[cg * 4 + j];  // numpy expr order
        int ci = C0 + cg * 4 + j;
        if (d < best[i]) { best[i] = d; bidx[i] = ci; }   // ascending ci => lowest idx kept
      }
  }
#pragma unroll
  for (int off = 8; off >= 1; off >>= 1) {
#pragma unroll
    for (int i = 0; i < 4; ++i) {
      float ov = __shfl_xor(best[i], off);
      int oi = __shfl_xor(bidx[i], off);
      if (ov < best[i] || (ov == best[i] && oi < bidx[i])) { best[i] = ov; bidx[i] = oi; }
    }
  }
  if (cg == 0) {
#pragma unroll
    for (int i = 0; i < 4; ++i) {
      int r = R0 + rg * 4 + i;
      if (r < N_NODES) vqidx[r] = bidx[i];
    }
  }
}

// ---------------------------------------------------------------- post + fc
__global__ void k_post(const float* __restrict__ h, const float* __restrict__ cbk,
                       const int* __restrict__ vqidx, const float* __restrict__ score,
                       const int* __restrict__ batch,
                       float* __restrict__ cacc, float* __restrict__ sacc,
                       float* __restrict__ cmt) {
  int w = (blockIdx.x * blockDim.x + threadIdx.x) >> 6;
  int lane = threadIdx.x & 63;
  if (w >= N_NODES) return;
  int b = batch[w];
  float sc = score[w];
  int qi = vqidx[w];
  float2 nf = *(const float2*)&h[w * DIM + lane * 2];
  float2 q  = *(const float2*)&cbk[qi * DIM + lane * 2];
  float rx = nf.x + q.x, ry = nf.y + q.y;
  atomicAdd(&cacc[b * DIM + lane * 2],     rx * sc);
  atomicAdd(&cacc[b * DIM + lane * 2 + 1], ry * sc);
  atomicAdd(&sacc[b * DIM + lane * 2],     rx * (1.f - sc));
  atomicAdd(&sacc[b * DIM + lane * 2 + 1], ry * (1.f - sc));
  float dx = q.x - nf.x, dy = q.y - nf.y;
  float dsq = dx * dx + dy * dy;
#pragma unroll
  for (int off = 32; off >= 1; off >>= 1) dsq += __shfl_down(dsq, off);
  if (lane == 0) atomicAdd(cmt, dsq);
}

__global__ void k_fc(const float* __restrict__ cacc, const float* __restrict__ sacc,
                     const float* __restrict__ W1, const float* __restrict__ b1,
                     const float* __restrict__ W2, const float* __restrict__ b2,
                     const float* __restrict__ cmt, float* __restrict__ out) {
  int g = blockIdx.x, t = threadIdx.x;
  int side = t >> 7, c = t & 127;
  __shared__ float sIn[2][128];
  if (t < 128) sIn[0][t] = cacc[g * DIM + t];
  else         sIn[1][t - 128] = sacc[g * DIM + (t - 128)];
  __syncthreads();
  const float* W = side ? W2 : W1;
  const float* b = side ? b2 : b1;
  float a = b[c];
  for (int k = 0; k < DIM; ++k) a += sIn[side][k] * W[k * DIM + c];
  out[side * (NG * DIM) + g * DIM + c] = fmaxf(a, 0.f);
  if (g == 0 && t == 0) out[2 * NG * DIM] = 0.25f * cmt[0] / (float)(N_NODES * DIM);
}

// ---------------------------------------------------------------- launch
extern "C" void kernel_launch(void* const* d_in, const int* in_sizes, int n_in,
                              void* d_out, int out_size, void* d_ws, size_t ws_size,
                              hipStream_t stream) {
  const float* x     = (const float*)d_in[0];
  const int*   ei    = (const int*)d_in[1];
  const int*   srcE  = ei;
  const int*   dstE  = ei + N_EDGES;
  const int*   batch = (const int*)d_in[2];
  const float* score = (const float*)d_in[3];
  const float* cW1   = (const float*)d_in[4];
  const float* cb1   = (const float*)d_in[5];
  const float* cW2   = (const float*)d_in[6];
  const float* cb2   = (const float*)d_in[7];
  const float* gam   = (const float*)d_in[8];
  const float* bet   = (const float*)d_in[9];
  const float* cbk   = (const float*)d_in[10];
  const float* fc1W  = (const float*)d_in[11];
  const float* fc1b  = (const float*)d_in[12];
  const float* fc2W  = (const float*)d_in[13];
  const float* fc2b  = (const float*)d_in[14];
  float* out = (float*)d_out;

  // workspace layout (elements)
  int*   deg    = (int*)d_ws;               // 20000
  int*   cursor = deg + N_NODES;            // 20000
  float* stats  = (float*)(cursor + N_NODES); // 5*256
  float* cmt    = stats + NL * 256;         // 1
  float* cacc   = cmt + 1;                  // 32768
  float* sacc   = cacc + NG * DIM;          // 32768
  int*   rowptr = (int*)(sacc + NG * DIM);  // 20001
  int*   eidx   = rowptr + (N_NODES + 1);   // 320000
  float* h      = (float*)(eidx + N_EDGES + 2); // 2560000 (16B aligned)
  float* z0     = h + N_NODES * DIM;        // 2560000
  float* c2     = z0 + N_NODES * DIM;       // 12032
  float* x2     = c2 + 12032;               // 20000
  int*   vqidx  = (int*)(x2 + N_NODES);     // 20000

  const size_t zero_bytes = (size_t)(2 * N_NODES + NL * 256 + 1 + 2 * NG * DIM) * 4;
  hipMemsetAsync(d_ws, 0, zero_bytes, stream);

  k_deg <<<(N_EDGES + 255) / 256, 256, 0, stream>>>(dstE, deg);
  k_scan<<<1, 256, 0, stream>>>(deg, rowptr);
  k_fill<<<(N_EDGES + 255) / 256, 256, 0, stream>>>(srcE, dstE, rowptr, cursor, eidx);
  k_rowsq_np<<<(CB * 8 + 255) / 256, 256, 0, stream>>>(cbk, c2, CB);

  for (int l = 0; l < NL; ++l) {
    const float* hin = (l == 0) ? x : h;
    k_gather<<<N_NODES / 4, 256, 0, stream>>>(hin, rowptr, eidx, z0);
    k_mlp<<<(N_NODES + 63) / 64, 256, 0, stream>>>(
        z0, cW1 + l * DIM * DIM, cb1 + l * DIM, cW2 + l * DIM * DIM, cb2 + l * DIM,
        h, stats + l * 256);
    k_bn<<<(N_NODES * DIM / 4 + 255) / 256, 256, 0, stream>>>(
        h, stats + l * 256, gam + l * DIM, bet + l * DIM);
  }

  k_rowsq_np<<<(N_NODES * 8 + 255) / 256, 256, 0, stream>>>(h, x2, N_NODES);
  k_vq<<<(N_NODES + 63) / 64, 256, 0, stream>>>(h, x2, cbk, c2, vqidx);
  k_post<<<N_NODES / 4, 256, 0, stream>>>(h, cbk, vqidx, score, batch, cacc, sacc, cmt);
  k_fc<<<NG, 256, 0, stream>>>(cacc, sacc, fc1W, fc1b, fc2W, fc2b, cmt, out);
}